// Round 2
// baseline (704.837 us; speedup 1.0000x reference)
//
#include <hip/hip_runtime.h>
#include <hip/hip_bf16.h>

#define TT 256   // tokens per batch
#define CC 384   // channels
#define HSZ 64   // head size

typedef __attribute__((ext_vector_type(8))) short bf16x8;
typedef __attribute__((ext_vector_type(4))) float f32x4;

static __device__ __forceinline__ unsigned short f2bf(float f) {
    union { __hip_bfloat16 h; unsigned short u; } cv;
    cv.h = __float2bfloat16(f);
    return cv.u;
}

// pack 8 fp32 (two float4) -> bf16x8 (RNE)
static __device__ __forceinline__ bf16x8 cvt8(float4 a, float4 b) {
    bf16x8 r;
    r[0] = (short)f2bf(a.x); r[1] = (short)f2bf(a.y);
    r[2] = (short)f2bf(a.z); r[3] = (short)f2bf(a.w);
    r[4] = (short)f2bf(b.x); r[5] = (short)f2bf(b.y);
    r[6] = (short)f2bf(b.z); r[7] = (short)f2bf(b.w);
    return r;
}

// ---- kernel 1: Wt[n][ck] = bf16(W_{n/64}[ck][n%64])  (n in [0,192), ck in [0,384)) ----
__global__ __launch_bounds__(256) void wtrans_kernel(
        const float* __restrict__ Wq,
        const float* __restrict__ Wk,
        const float* __restrict__ Wv,
        unsigned short* __restrict__ Wt) {
    int idx = blockIdx.x * 256 + threadIdx.x;
    if (idx >= 192 * CC) return;
    int n = idx / CC;
    int ck = idx - n * CC;
    const float* W = (n < 64) ? Wq : ((n < 128) ? Wk : Wv);
    Wt[n * CC + ck] = f2bf(W[ck * HSZ + (n & 63)]);
}

// ---- kernel 2: [q|k|v] = x @ Wt^T. q,k bf16 row-major [B*T][64]; v bf16 transposed [B][64][T] ----
__global__ __launch_bounds__(256, 2) void qkv_kernel(
        const float* __restrict__ x,
        const unsigned short* __restrict__ Wt,
        unsigned short* __restrict__ qw,
        unsigned short* __restrict__ kw,
        unsigned short* __restrict__ vtw) {
    const int lane = threadIdx.x & 63;
    const int wv   = threadIdx.x >> 6;
    const int c    = lane & 15;
    const int quad = lane >> 4;
    const int rowbase = blockIdx.x * 128 + wv * 32;  // 2 m-tiles of 16 rows per wave

    f32x4 acc[2][12];
    #pragma unroll
    for (int t = 0; t < 2; ++t)
        #pragma unroll
        for (int n = 0; n < 12; ++n)
            acc[t][n] = (f32x4){0.f, 0.f, 0.f, 0.f};

    const float* xa0 = x + (size_t)(rowbase + c) * CC + quad * 8;
    const float* xa1 = xa0 + 16 * CC;
    const unsigned short* wb = Wt + c * CC + quad * 8;

    for (int s = 0; s < 12; ++s) {
        float4 a0lo = *(const float4*)(xa0 + s * 32);
        float4 a0hi = *(const float4*)(xa0 + s * 32 + 4);
        float4 a1lo = *(const float4*)(xa1 + s * 32);
        float4 a1hi = *(const float4*)(xa1 + s * 32 + 4);
        bf16x8 a0 = cvt8(a0lo, a0hi);
        bf16x8 a1 = cvt8(a1lo, a1hi);
        #pragma unroll
        for (int n = 0; n < 12; ++n) {
            bf16x8 b = *(const bf16x8*)(wb + n * 16 * CC + s * 32);
            acc[0][n] = __builtin_amdgcn_mfma_f32_16x16x32_bf16(a0, b, acc[0][n], 0, 0, 0);
            acc[1][n] = __builtin_amdgcn_mfma_f32_16x16x32_bf16(a1, b, acc[1][n], 0, 0, 0);
        }
    }

    #pragma unroll
    for (int t = 0; t < 2; ++t) {
        const int mbase = rowbase + t * 16 + quad * 4;  // + r gives global row
        #pragma unroll
        for (int n = 0; n < 8; ++n) {  // q (0..3), k (4..7)
            unsigned short* dst = (n < 4) ? qw : kw;
            const int cg = (n & 3) * 16 + c;
            #pragma unroll
            for (int r = 0; r < 4; ++r)
                dst[(size_t)(mbase + r) * HSZ + cg] = f2bf(acc[t][n][r]);
        }
        // v: store transposed [b][hs][tok]; 4 consecutive tokens -> packed 8B store
        const int bidx = mbase >> 8;
        const int tok  = mbase & 255;
        #pragma unroll
        for (int n = 8; n < 12; ++n) {
            const int hsg = (n - 8) * 16 + c;
            ushort4 pk;
            pk.x = f2bf(acc[t][n][0]);
            pk.y = f2bf(acc[t][n][1]);
            pk.z = f2bf(acc[t][n][2]);
            pk.w = f2bf(acc[t][n][3]);
            *(ushort4*)(vtw + (size_t)bidx * (HSZ * TT) + hsg * TT + tok) = pk;
        }
    }
}

// ---- kernel 3: causal flash attention, one workgroup (4 waves) per batch; fp32 out ----
__global__ __launch_bounds__(256, 2) void attn_kernel(
        const unsigned short* __restrict__ qw,
        const unsigned short* __restrict__ kw,
        const unsigned short* __restrict__ vtw,
        float* __restrict__ outp) {
    __shared__ __align__(16) unsigned short pbuf[4][16][40];  // per-wave P tile, stride 40 (16B-aligned rows)
    const int b    = blockIdx.x;
    const int lane = threadIdx.x & 63;
    const int wv   = threadIdx.x >> 6;
    const int c    = lane & 15;
    const int quad = lane >> 4;

    const unsigned short* qb = qw  + (size_t)b * TT * HSZ;
    const unsigned short* kb = kw  + (size_t)b * TT * HSZ;
    const unsigned short* vb = vtw + (size_t)b * HSZ * TT;
    float*                ob = outp + (size_t)b * TT * HSZ;

    // Q fragments: wave wv handles m-tiles {wv, wv+4, wv+8, wv+12} (balanced causal work)
    bf16x8 qf[4][2];
    #pragma unroll
    for (int i = 0; i < 4; ++i) {
        const int rb = (wv + 4 * i) * 16;
        #pragma unroll
        for (int ks = 0; ks < 2; ++ks)
            qf[i][ks] = *(const bf16x8*)(qb + (rb + c) * HSZ + ks * 32 + quad * 8);
    }

    f32x4 of[4][4];
    f32x4 mst[4], lst[4];
    #pragma unroll
    for (int i = 0; i < 4; ++i) {
        mst[i] = (f32x4){-1e30f, -1e30f, -1e30f, -1e30f};
        lst[i] = (f32x4){0.f, 0.f, 0.f, 0.f};
        #pragma unroll
        for (int n = 0; n < 4; ++n)
            of[i][n] = (f32x4){0.f, 0.f, 0.f, 0.f};
    }

    const float qscale = 0.18033688011112042f;  // (1/sqrt(64)) * log2(e)

    for (int kt = 0; kt < 8; ++kt) {
        const int k0 = kt * 32;
        bf16x8 kf[2][2], vf[4];
        #pragma unroll
        for (int nt = 0; nt < 2; ++nt)
            #pragma unroll
            for (int ks = 0; ks < 2; ++ks)
                kf[nt][ks] = *(const bf16x8*)(kb + (k0 + nt * 16 + c) * HSZ + ks * 32 + quad * 8);
        #pragma unroll
        for (int n = 0; n < 4; ++n)
            vf[n] = *(const bf16x8*)(vb + (n * 16 + c) * TT + k0 + quad * 8);

        #pragma unroll
        for (int i = 0; i < 4; ++i) {
            const int mt = wv + 4 * i;
            if (mt < 2 * kt) continue;  // tile fully above diagonal (wave-uniform)
            const int rb = mt * 16;

            f32x4 s0 = {0.f, 0.f, 0.f, 0.f}, s1 = {0.f, 0.f, 0.f, 0.f};
            #pragma unroll
            for (int ks = 0; ks < 2; ++ks) {
                s0 = __builtin_amdgcn_mfma_f32_16x16x32_bf16(qf[i][ks], kf[0][ks], s0, 0, 0, 0);
                s1 = __builtin_amdgcn_mfma_f32_16x16x32_bf16(qf[i][ks], kf[1][ks], s1, 0, 0, 0);
            }

            f32x4 t0, t1;
            #pragma unroll
            for (int r = 0; r < 4; ++r) { t0[r] = s0[r] * qscale; t1[r] = s1[r] * qscale; }

            if (mt < 2 * kt + 2) {  // diagonal-adjacent: apply causal mask
                #pragma unroll
                for (int r = 0; r < 4; ++r) {
                    const int row = rb + quad * 4 + r;
                    if (k0 + c > row)      t0[r] = -1e30f;
                    if (k0 + 16 + c > row) t1[r] = -1e30f;
                }
            }

            // row max over 16 cols (lanes sharing a quad)
            f32x4 mx;
            #pragma unroll
            for (int r = 0; r < 4; ++r) mx[r] = fmaxf(t0[r], t1[r]);
            #pragma unroll
            for (int off = 1; off < 16; off <<= 1)
                #pragma unroll
                for (int r = 0; r < 4; ++r)
                    mx[r] = fmaxf(mx[r], __shfl_xor(mx[r], off, 64));

            f32x4 mnew, alpha, p0, p1, rs;
            #pragma unroll
            for (int r = 0; r < 4; ++r) {
                mnew[r]  = fmaxf(mst[i][r], mx[r]);
                alpha[r] = exp2f(mst[i][r] - mnew[r]);
                p0[r]    = exp2f(t0[r] - mnew[r]);
                p1[r]    = exp2f(t1[r] - mnew[r]);
                rs[r]    = p0[r] + p1[r];
                mst[i][r] = mnew[r];
            }
            #pragma unroll
            for (int off = 1; off < 16; off <<= 1)
                #pragma unroll
                for (int r = 0; r < 4; ++r)
                    rs[r] += __shfl_xor(rs[r], off, 64);
            #pragma unroll
            for (int r = 0; r < 4; ++r)
                lst[i][r] = lst[i][r] * alpha[r] + rs[r];

            #pragma unroll
            for (int n = 0; n < 4; ++n)
                #pragma unroll
                for (int r = 0; r < 4; ++r)
                    of[i][n][r] *= alpha[r];

            // P: C-layout -> LDS -> A-layout (wave-private buffer; same-wave DS ops are in-order)
            #pragma unroll
            for (int r = 0; r < 4; ++r) {
                pbuf[wv][quad * 4 + r][c]      = f2bf(p0[r]);
                pbuf[wv][quad * 4 + r][16 + c] = f2bf(p1[r]);
            }
            bf16x8 pf = *(const bf16x8*)(&pbuf[wv][c][quad * 8]);
            #pragma unroll
            for (int n = 0; n < 4; ++n)
                of[i][n] = __builtin_amdgcn_mfma_f32_16x16x32_bf16(pf, vf[n], of[i][n], 0, 0, 0);
        }
    }

    #pragma unroll
    for (int i = 0; i < 4; ++i) {
        const int rb = (wv + 4 * i) * 16;
        f32x4 inv;
        #pragma unroll
        for (int r = 0; r < 4; ++r) inv[r] = 1.f / lst[i][r];
        #pragma unroll
        for (int n = 0; n < 4; ++n)
            #pragma unroll
            for (int r = 0; r < 4; ++r)
                ob[(size_t)(rb + quad * 4 + r) * HSZ + n * 16 + c] = of[i][n][r] * inv[r];
    }
}

extern "C" void kernel_launch(void* const* d_in, const int* in_sizes, int n_in,
                              void* d_out, int out_size, void* d_ws, size_t ws_size,
                              hipStream_t stream) {
    const float* x  = (const float*)d_in[0];
    const float* Wq = (const float*)d_in[1];
    const float* Wk = (const float*)d_in[2];
    const float* Wv = (const float*)d_in[3];
    float* outp = (float*)d_out;

    const int Bn = in_sizes[0] / (TT * CC);  // 1024
    const size_t QKV_BYTES = (size_t)Bn * TT * HSZ * 2;  // 33554432 (bf16)

    char* ws = (char*)d_ws;
    unsigned short* Wt  = (unsigned short*)ws;                               // 147456 B used
    unsigned short* qw  = (unsigned short*)(ws + (1u << 18));
    unsigned short* kw  = (unsigned short*)(ws + (1u << 18) + QKV_BYTES);
    unsigned short* vtw = (unsigned short*)(ws + (1u << 18) + 2 * QKV_BYTES);

    hipLaunchKernelGGL(wtrans_kernel, dim3(288), dim3(256), 0, stream, Wq, Wk, Wv, Wt);
    hipLaunchKernelGGL(qkv_kernel, dim3(Bn * 2), dim3(256), 0, stream, x, Wt, qw, kw, vtw);
    hipLaunchKernelGGL(attn_kernel, dim3(Bn), dim3(256), 0, stream, qw, kw, vtw, outp);
}

// Round 3
// 660.270 us; speedup vs baseline: 1.0675x; 1.0675x over previous
//
#include <hip/hip_runtime.h>
#include <hip/hip_bf16.h>

#define TT 256   // tokens per batch
#define CC 384   // channels
#define HSZ 64   // head size

typedef __attribute__((ext_vector_type(8))) short bf16x8;
typedef __attribute__((ext_vector_type(4))) float f32x4;

static __device__ __forceinline__ unsigned short f2bf(float f) {
    union { __hip_bfloat16 h; unsigned short u; } cv;
    cv.h = __float2bfloat16(f);
    return cv.u;
}

// pack 8 fp32 (two float4) -> bf16x8 (RNE)
static __device__ __forceinline__ bf16x8 cvt8(float4 a, float4 b) {
    bf16x8 r;
    r[0] = (short)f2bf(a.x); r[1] = (short)f2bf(a.y);
    r[2] = (short)f2bf(a.z); r[3] = (short)f2bf(a.w);
    r[4] = (short)f2bf(b.x); r[5] = (short)f2bf(b.y);
    r[6] = (short)f2bf(b.z); r[7] = (short)f2bf(b.w);
    return r;
}

// ---- kernel 1: Wt[n][ck] = bf16(W_{n/64}[ck][n%64])  (n in [0,192), ck in [0,384)) ----
__global__ __launch_bounds__(256) void wtrans_kernel(
        const float* __restrict__ Wq,
        const float* __restrict__ Wk,
        const float* __restrict__ Wv,
        unsigned short* __restrict__ Wt) {
    int idx = blockIdx.x * 256 + threadIdx.x;
    if (idx >= 192 * CC) return;
    int n = idx / CC;
    int ck = idx - n * CC;
    const float* W = (n < 64) ? Wq : ((n < 128) ? Wk : Wv);
    Wt[n * CC + ck] = f2bf(W[ck * HSZ + (n & 63)]);
}

// ---- kernel 2: fused QKV + causal flash attention. One WG (8 waves) per batch. ----
// Phase 1: each wave computes 2 16-row tiles of q,k,v (rows {16w, 240-16w}).
//          k -> k_lds[token][hs] (stride 72), v -> v_lds[hs][token] (stride 264),
//          q -> A-frags in registers via per-wave pbuf transpose.
// Phase 2: flash attention; wave w owns m-tiles {w, 15-w} (balanced causal work).
__global__ __launch_bounds__(512, 2) void fused_kernel(
        const float* __restrict__ x,
        const unsigned short* __restrict__ Wt,
        float* __restrict__ outp) {
    __shared__ __align__(16) unsigned short k_lds[TT][72];    // 36 KB, pad 8 -> bank-uniform b128
    __shared__ __align__(16) unsigned short v_lds[HSZ][264];  // 33.8 KB
    __shared__ __align__(16) unsigned short pbuf[8][16][40];  // 10 KB, per-wave scratch

    const int b    = blockIdx.x;
    const int lane = threadIdx.x & 63;
    const int w    = threadIdx.x >> 6;   // wave 0..7
    const int c    = lane & 15;
    const int quad = lane >> 4;

    const int Rl0 = 16 * w;        // tile 0 rows (m-tile w)
    const int Rl1 = 240 - 16 * w;  // tile 1 rows (m-tile 15-w)

    // ---------------- phase 1: QKV projection ----------------
    f32x4 acc[2][12];
    #pragma unroll
    for (int t = 0; t < 2; ++t)
        #pragma unroll
        for (int n = 0; n < 12; ++n)
            acc[t][n] = (f32x4){0.f, 0.f, 0.f, 0.f};

    const float* xa0 = x + ((size_t)b * TT + Rl0 + c) * CC + quad * 8;
    const float* xa1 = x + ((size_t)b * TT + Rl1 + c) * CC + quad * 8;
    const unsigned short* wb = Wt + c * CC + quad * 8;

    for (int s = 0; s < 12; ++s) {
        float4 a0lo = *(const float4*)(xa0 + s * 32);
        float4 a0hi = *(const float4*)(xa0 + s * 32 + 4);
        float4 a1lo = *(const float4*)(xa1 + s * 32);
        float4 a1hi = *(const float4*)(xa1 + s * 32 + 4);
        bf16x8 a0 = cvt8(a0lo, a0hi);
        bf16x8 a1 = cvt8(a1lo, a1hi);
        #pragma unroll
        for (int n = 0; n < 12; ++n) {
            bf16x8 bf = *(const bf16x8*)(wb + n * 16 * CC + s * 32);
            acc[0][n] = __builtin_amdgcn_mfma_f32_16x16x32_bf16(a0, bf, acc[0][n], 0, 0, 0);
            acc[1][n] = __builtin_amdgcn_mfma_f32_16x16x32_bf16(a1, bf, acc[1][n], 0, 0, 0);
        }
    }

    // epilogue: scatter k, v to LDS; transpose q to A-frags via per-wave pbuf
    bf16x8 qf[2][2];
    #pragma unroll
    for (int t = 0; t < 2; ++t) {
        const int lr = (t == 0 ? Rl0 : Rl1) + quad * 4;  // + r gives local token row
        // k: n-tiles 4..7 -> k_lds[token][hs]
        #pragma unroll
        for (int n = 4; n < 8; ++n) {
            const int cg = (n - 4) * 16 + c;
            #pragma unroll
            for (int r = 0; r < 4; ++r)
                k_lds[lr + r][cg] = f2bf(acc[t][n][r]);
        }
        // v: n-tiles 8..11 -> v_lds[hs][token], 4 consecutive tokens packed
        #pragma unroll
        for (int n = 8; n < 12; ++n) {
            const int hsg = (n - 8) * 16 + c;
            ushort4 pk;
            pk.x = f2bf(acc[t][n][0]);
            pk.y = f2bf(acc[t][n][1]);
            pk.z = f2bf(acc[t][n][2]);
            pk.w = f2bf(acc[t][n][3]);
            *(ushort4*)(&v_lds[hsg][lr]) = pk;
        }
        // q: n-tiles 0..3, C-layout -> pbuf -> A-layout frags (two 32-col passes)
        #pragma unroll
        for (int p = 0; p < 2; ++p) {
            #pragma unroll
            for (int n2 = 0; n2 < 2; ++n2) {
                const int n = 2 * p + n2;
                #pragma unroll
                for (int r = 0; r < 4; ++r)
                    pbuf[w][quad * 4 + r][n2 * 16 + c] = f2bf(acc[t][n][r]);
            }
            qf[t][p] = *(const bf16x8*)(&pbuf[w][c][quad * 8]);
        }
    }

    __syncthreads();

    // ---------------- phase 2: causal flash attention ----------------
    const int mt0 = w;
    const int mt1 = 15 - w;  // mt1 >= mt0

    f32x4 of[2][4];
    f32x4 mst[2], lst[2];
    #pragma unroll
    for (int i = 0; i < 2; ++i) {
        mst[i] = (f32x4){-1e30f, -1e30f, -1e30f, -1e30f};
        lst[i] = (f32x4){0.f, 0.f, 0.f, 0.f};
        #pragma unroll
        for (int n = 0; n < 4; ++n)
            of[i][n] = (f32x4){0.f, 0.f, 0.f, 0.f};
    }

    const float qscale = 0.18033688011112042f;  // (1/sqrt(64)) * log2(e)

    for (int kt = 0; kt < 8; ++kt) {
        if (mt1 < 2 * kt) break;  // both tiles done (wave-uniform)
        const int k0 = kt * 32;

        bf16x8 kf[2][2], vf[4];
        #pragma unroll
        for (int nt = 0; nt < 2; ++nt)
            #pragma unroll
            for (int ks = 0; ks < 2; ++ks)
                kf[nt][ks] = *(const bf16x8*)(&k_lds[k0 + nt * 16 + c][ks * 32 + quad * 8]);
        #pragma unroll
        for (int n = 0; n < 4; ++n)
            vf[n] = *(const bf16x8*)(&v_lds[n * 16 + c][k0 + quad * 8]);

        #pragma unroll
        for (int ti = 0; ti < 2; ++ti) {
            const int mt = (ti == 0) ? mt0 : mt1;
            if (mt < 2 * kt) continue;
            const int rb = mt * 16;

            f32x4 s0 = {0.f, 0.f, 0.f, 0.f}, s1 = {0.f, 0.f, 0.f, 0.f};
            #pragma unroll
            for (int ks = 0; ks < 2; ++ks) {
                s0 = __builtin_amdgcn_mfma_f32_16x16x32_bf16(qf[ti][ks], kf[0][ks], s0, 0, 0, 0);
                s1 = __builtin_amdgcn_mfma_f32_16x16x32_bf16(qf[ti][ks], kf[1][ks], s1, 0, 0, 0);
            }

            f32x4 t0, t1;
            #pragma unroll
            for (int r = 0; r < 4; ++r) { t0[r] = s0[r] * qscale; t1[r] = s1[r] * qscale; }

            if (mt < 2 * kt + 2) {  // diagonal-adjacent: causal mask
                #pragma unroll
                for (int r = 0; r < 4; ++r) {
                    const int row = rb + quad * 4 + r;
                    if (k0 + c > row)      t0[r] = -1e30f;
                    if (k0 + 16 + c > row) t1[r] = -1e30f;
                }
            }

            // row max over 16 cols
            f32x4 mx;
            #pragma unroll
            for (int r = 0; r < 4; ++r) mx[r] = fmaxf(t0[r], t1[r]);
            #pragma unroll
            for (int off = 1; off < 16; off <<= 1)
                #pragma unroll
                for (int r = 0; r < 4; ++r)
                    mx[r] = fmaxf(mx[r], __shfl_xor(mx[r], off, 64));

            f32x4 mnew, alpha, p0, p1, rs;
            #pragma unroll
            for (int r = 0; r < 4; ++r) {
                mnew[r]  = fmaxf(mst[ti][r], mx[r]);
                alpha[r] = exp2f(mst[ti][r] - mnew[r]);
                p0[r]    = exp2f(t0[r] - mnew[r]);
                p1[r]    = exp2f(t1[r] - mnew[r]);
                rs[r]    = p0[r] + p1[r];
                mst[ti][r] = mnew[r];
            }
            #pragma unroll
            for (int off = 1; off < 16; off <<= 1)
                #pragma unroll
                for (int r = 0; r < 4; ++r)
                    rs[r] += __shfl_xor(rs[r], off, 64);
            #pragma unroll
            for (int r = 0; r < 4; ++r)
                lst[ti][r] = lst[ti][r] * alpha[r] + rs[r];

            #pragma unroll
            for (int n = 0; n < 4; ++n)
                #pragma unroll
                for (int r = 0; r < 4; ++r)
                    of[ti][n][r] *= alpha[r];

            // P: C-layout -> pbuf -> A-layout
            #pragma unroll
            for (int r = 0; r < 4; ++r) {
                pbuf[w][quad * 4 + r][c]      = f2bf(p0[r]);
                pbuf[w][quad * 4 + r][16 + c] = f2bf(p1[r]);
            }
            bf16x8 pf = *(const bf16x8*)(&pbuf[w][c][quad * 8]);
            #pragma unroll
            for (int n = 0; n < 4; ++n)
                of[ti][n] = __builtin_amdgcn_mfma_f32_16x16x32_bf16(pf, vf[n], of[ti][n], 0, 0, 0);
        }
    }

    // epilogue: normalize and store fp32
    float* ob = outp + (size_t)b * TT * HSZ;
    #pragma unroll
    for (int ti = 0; ti < 2; ++ti) {
        const int rb = ((ti == 0) ? mt0 : mt1) * 16;
        f32x4 inv;
        #pragma unroll
        for (int r = 0; r < 4; ++r) inv[r] = 1.f / lst[ti][r];
        #pragma unroll
        for (int n = 0; n < 4; ++n)
            #pragma unroll
            for (int r = 0; r < 4; ++r)
                ob[(size_t)(rb + quad * 4 + r) * HSZ + n * 16 + c] = of[ti][n][r] * inv[r];
    }
}

extern "C" void kernel_launch(void* const* d_in, const int* in_sizes, int n_in,
                              void* d_out, int out_size, void* d_ws, size_t ws_size,
                              hipStream_t stream) {
    const float* x  = (const float*)d_in[0];
    const float* Wq = (const float*)d_in[1];
    const float* Wk = (const float*)d_in[2];
    const float* Wv = (const float*)d_in[3];
    float* outp = (float*)d_out;

    const int Bn = in_sizes[0] / (TT * CC);  // 1024

    unsigned short* Wt = (unsigned short*)d_ws;  // 147456 B used

    hipLaunchKernelGGL(wtrans_kernel, dim3(288), dim3(256), 0, stream, Wq, Wk, Wv, Wt);
    hipLaunchKernelGGL(fused_kernel, dim3(Bn), dim3(512), 0, stream, x, Wt, outp);
}